// Round 16
// baseline (21360.464 us; speedup 1.0000x reference)
//
#include <hip/hip_runtime.h>

// PhasedLSTM: S=1024, B=64, H=512, L=2. Persistent-kernel pipelined recurrence
// (R6 structure, proven correct at 21.4ms) + R16 fix: all hot-path ring stores
// are COALESCED to full-line NT vector stores via LDS staging. R6's cost was
// ~160K sub-line (2-4B) sc1 store transactions/phase = MALL RMWs ~15us/phase.
// Phase q: XP computes Xpre[q]=x[q]@Wxh0^T+b0 ; G0 computes h0[q-1] ; G1
// computes h1[q-2]. One device-wide barrier per phase (two-level aggregated).
// h1 ring re-laid out block-major [grp][64 b][16 u] so each block's slice is a
// contiguous 2KB run (reader = G1 only; its prefetch indices adjusted).
// t<=8 phases: exact fp32 VALU path (time-gate k=2phi/RHO reaches -40; gate
// error amplified ~k^3 -> bf16 insufficient). t>=9: k<=1 -> bf16 MFMA path.

#define NBLK 64
#define TPREC 8

// d_ws byte offsets
#define OFF_ARR   0               // blocks 0..62: arrival lines; line 63 = epoch word
#define OFF_H0    4096            // 2 slots x [64][512] bf16 (standard layout)
#define OFF_H1    266240          // 2 slots x [32 grp][64 b][16 u] bf16 (block-major)
#define OFF_H0F   528384          // 2 slots x [512 u][64 b] f32 (early-phase operand)
#define OFF_H1F   1052672
#define OFF_C0    1576960         // [64 b][512 u] f32 cell state (block-private, cached)
#define OFF_C1    1708032
#define OFF_XPRE  1839104         // 2 slots x [64 b][2048 n] f32
#define OFF_KTAB  2887680         // [1024 t][2 l][512 u] f32
#define OFF_W0    7081984         // 16 blk x [128][512]  bf16 (gate-grouped Whh0)
#define OFF_W1    9179136         // 32 blk x [64][1024]  bf16 ([Wxh1 ; Whh1])
#define OFF_WX    13373440        // 16 blk x [128][512]  bf16 (Wxh0)

#define HB_SLOT   65536
#define HF_SLOT   131072
#define XP_SLOT   524288

typedef float  f32x4  __attribute__((ext_vector_type(4)));
typedef int    i32x4  __attribute__((ext_vector_type(4)));
typedef __bf16 bf16x8 __attribute__((ext_vector_type(8)));
typedef unsigned long long u64;

static __device__ __forceinline__ unsigned short f2bf(float f) {
  unsigned u = __builtin_bit_cast(unsigned, f);
  u += 0x7FFFu + ((u >> 16) & 1u);        // RNE
  return (unsigned short)(u >> 16);
}
static __device__ __forceinline__ float sigm(float x) { return 1.0f / (1.0f + __expf(-x)); }
static __device__ __forceinline__ float tanhfast(float x) { return 1.0f - 2.0f / (__expf(2.0f * x) + 1.0f); }

// AGENT-scope (cross-XCD coherent) ring ops, compiler-managed loads.
static __device__ __forceinline__ i32x4 ring_load16(const void* p) {
  const u64* q = (const u64*)p;
  u64 lo = __hip_atomic_load(q + 0, __ATOMIC_RELAXED, __HIP_MEMORY_SCOPE_AGENT);
  u64 hi = __hip_atomic_load(q + 1, __ATOMIC_RELAXED, __HIP_MEMORY_SCOPE_AGENT);
  i32x4 r;
  r[0] = (int)(unsigned)(lo & 0xFFFFFFFFull);
  r[1] = (int)(unsigned)(lo >> 32);
  r[2] = (int)(unsigned)(hi & 0xFFFFFFFFull);
  r[3] = (int)(unsigned)(hi >> 32);
  return r;
}
static __device__ __forceinline__ float ring_loadf(const void* p) {
  return __hip_atomic_load((const float*)p, __ATOMIC_RELAXED, __HIP_MEMORY_SCOPE_AGENT);
}
static __device__ __forceinline__ void ring_storef(void* p, float v) {
  __hip_atomic_store((float*)p, v, __ATOMIC_RELAXED, __HIP_MEMORY_SCOPE_AGENT);
}
static __device__ __forceinline__ void ring_store_u16(void* p, unsigned v) {
  asm volatile("global_store_short %0, %1, off sc0 sc1" :: "v"(p), "v"(v) : "memory");
}
// NEW: full 16B NT store (stores have no dest-register hazard)
static __device__ __forceinline__ void ring_store16(void* p, i32x4 v) {
  asm volatile("global_store_dwordx4 %0, %1, off sc0 sc1" :: "v"(p), "v"(v) : "memory");
}
static __device__ __forceinline__ unsigned flag_load(const unsigned* p) {
  return __hip_atomic_load(p, __ATOMIC_RELAXED, __HIP_MEMORY_SCOPE_AGENT);
}
static __device__ __forceinline__ void flag_store(unsigned* p, unsigned v) {
  __hip_atomic_store(p, v, __ATOMIC_RELAXED, __HIP_MEMORY_SCOPE_AGENT);
}

static __device__ __forceinline__ f32x4 mfma16(bf16x8 a, bf16x8 b, f32x4 c) {
  return __builtin_amdgcn_mfma_f32_16x16x32_bf16(a, b, c, 0, 0, 0);
}
static __device__ __forceinline__ bf16x8 lds_frag(const char* p) {
  return __builtin_bit_cast(bf16x8, *(const i32x4*)p);
}

// ---------------- prep: bf16 weight relayout + time-gate table (R6 verbatim) ----------------
__global__ void plstm_prep(const float* __restrict__ Wxh_w, const float* __restrict__ Whh_w,
                           const float* __restrict__ times, const float* __restrict__ tau,
                           const float* __restrict__ s_p, unsigned char* __restrict__ ws) {
  const int idx = blockIdx.x * 256 + threadIdx.x;
  const int stride = gridDim.x * 256;
  for (int e = idx; e < 1048576; e += stride) {
    int g = e >> 16, j = (e >> 9) & 127, k = e & 511;
    int gate = j >> 5, u = g * 32 + (j & 31);
    ((unsigned short*)(ws + OFF_W0))[e] = f2bf(Whh_w[(gate * 512 + u) * 512 + k]);
  }
  for (int e = idx; e < 2097152; e += stride) {
    int g = e >> 16, j = (e >> 10) & 63, k = e & 1023;
    int gate = j >> 4, row = gate * 512 + g * 16 + (j & 15);
    float v = (k < 512) ? Wxh_w[1048576 + row * 512 + k] : Whh_w[1048576 + row * 512 + (k - 512)];
    ((unsigned short*)(ws + OFF_W1))[e] = f2bf(v);
  }
  for (int e = idx; e < 1048576; e += stride) {
    int g = e >> 16, j = (e >> 9) & 127, k = e & 511;
    ((unsigned short*)(ws + OFF_WX))[e] = f2bf(Wxh_w[(g * 128 + j) * 512 + k]);
  }
  for (int e = idx; e < 1048576; e += stride) {
    int t = e >> 10, r = e & 1023, l = r >> 9, u = r & 511;
    float phi = fmodf(times[t] - s_p[l * 512 + u], tau[l * 512 + u]) / tau[l * 512 + u];
    float kv;
    if (phi < 0.025f)      kv = phi * 40.0f;
    else if (phi < 0.05f)  kv = 2.0f - phi * 40.0f;
    else                   kv = 0.001f * phi;
    ((float*)(ws + OFF_KTAB))[e] = kv;
  }
}

// ---------------- main persistent kernel ----------------
__global__ void __launch_bounds__(256, 1)
plstm_main(const float* __restrict__ xin, const float* __restrict__ bias,
           const float* __restrict__ Wxh_w, const float* __restrict__ Whh_w,
           float* __restrict__ out, unsigned char* __restrict__ wsu) {
  __shared__ char Wl[131072];   // bf16 weights, LDS-resident for whole kernel
  __shared__ char Al[16384];    // A staging / f32 redistribution / epilogue staging

  const char* ws = (const char*)wsu;
  char* wsw = (char*)wsu;
  const int bid = blockIdx.x, tid = threadIdx.x;
  const int lane = tid & 63, wv = tid >> 6;
  const int lq = lane >> 4, lr = lane & 15;
  const int role = (bid < 16) ? 0 : (bid < 48) ? 1 : 2;
  const int grp = (role == 0) ? bid : (role == 1) ? bid - 16 : bid - 48;

  unsigned* arr = (unsigned*)(wsw + OFF_ARR);          // lines 0..62: arrivals
  unsigned* epoch = (unsigned*)(wsw + OFF_ARR + 4032); // line 63: epoch
  const float* ktabp = (const float*)(ws + OFF_KTAB);
  const float* bias0 = bias;
  const float* bias1 = bias + 2048;
  float* Alf = (float*)Al;

  // --- bf16 W slice -> LDS (swizzle: byte ^= (row&7)<<4) ---
  {
    const char* wsrc = ws +
      ((role == 0) ? (OFF_W0 + grp * 131072) : (role == 1) ? (OFF_W1 + grp * 131072)
                                             : (OFF_WX + grp * 131072));
    const int kshift = (role == 1) ? 10 : 9;
    for (int e = tid * 8; e < 65536; e += 2048) {
      i32x4 v = *(const i32x4*)(wsrc + e * 2);
      int row = e >> kshift;
      *(i32x4*)(Wl + ((e * 2) ^ ((row & 7) << 4))) = v;
    }
    __syncthreads();
  }

  for (int q = 0; q < 1026; ++q) {
    if (role == 0) {
      // ================ G0: h0 for t0 = q-1 ================
      if (q >= 1 && q <= 1024) {
        const int t0 = q - 1;
        const char* xpre = ws + OFF_XPRE + (t0 & 1) * XP_SLOT;
        char* c0p = wsw + OFF_C0;
        char* h0bw = wsw + OFF_H0 + (t0 & 1) * HB_SLOT;

        if (t0 <= TPREC) {
          // ---- exact fp32 path (R6 verbatim; scalar stores, 9 phases only) ----
          const int rp = tid >> 4, bq = tid & 15;
          const int gate = rp >> 2;
          const int u0 = grp * 32 + (rp & 3) * 8;
          const float* w8 = Whh_w + (size_t)(gate * 512 + u0) * 512;
          const char* hsrc = ws + OFF_H0F + ((t0 - 1) & 1) * HF_SLOT;
          f32x4 acc8[8] = {};
          for (int kc = 0; kc < 8; ++kc) {
            __syncthreads();
            for (int i = 0; i < 4; ++i) {
              int qi = tid + 256 * i, k = qi >> 4, b4 = qi & 15;
              i32x4 v = ring_load16(hsrc + ((kc * 64 + k) * 64 + b4 * 4) * 4);
              *(i32x4*)(Alf + k * 64 + b4 * 4) = v;
            }
            __syncthreads();
            for (int kb = 0; kb < 16; ++kb) {
              f32x4 w4[8];
#pragma unroll
              for (int r = 0; r < 8; ++r) w4[r] = *(const f32x4*)(w8 + r * 512 + kc * 64 + kb * 4);
#pragma unroll
              for (int ks = 0; ks < 4; ++ks) {
                f32x4 hv = *(const f32x4*)(Alf + (kb * 4 + ks) * 64 + bq * 4);
#pragma unroll
                for (int r = 0; r < 8; ++r) acc8[r] += w4[r][ks] * hv;
              }
            }
          }
          char* h0fw = wsw + OFF_H0F + (t0 & 1) * HF_SLOT;
          for (int ph = 0; ph < 2; ++ph) {
            __syncthreads();
            if ((bq >> 3) == ph) {
#pragma unroll
              for (int r = 0; r < 8; ++r)
                *(f32x4*)(Alf + (rp * 8 + r) * 32 + (bq & 7) * 4) = acc8[r];
            }
            __syncthreads();
            for (int i = 0; i < 4; ++i) {
              int e = tid + 256 * i;
              int u = e >> 5, b32 = e & 31, b = ph * 32 + b32;
              int ucol = grp * 32 + u;
              float g4[4];
#pragma unroll
              for (int gt = 0; gt < 4; ++gt)
                g4[gt] = Alf[(gt * 32 + u) * 32 + b32]
                       + ring_loadf(xpre + (b * 2048 + gt * 512 + ucol) * 4);
              const float kk = ktabp[t0 * 1024 + ucol];
              const float cold = *(const float*)(c0p + (b * 512 + ucol) * 4);
              const float itg = sigm(g4[0]) * kk;
              const float ftg = sigm(g4[1] + 1.0f - kk);
              const float gtg = tanhfast(g4[2]) * kk;
              const float otg = sigm(g4[3]) * kk;
              const float cn = ftg * cold + itg * gtg;
              const float hn = otg * tanhfast(cn);
              *(float*)(c0p + (b * 512 + ucol) * 4) = cn;
              ring_store_u16(h0bw + (b * 512 + ucol) * 2, (unsigned)f2bf(hn));
              ring_storef(h0fw + (ucol * 64 + b) * 4, hn);
            }
          }
        } else {
          // ---- bf16 MFMA fast path (LDS-staged A) ----
          const int uf = wv >> 1, mh = wv & 1;
          const int ucol = grp * 32 + uf * 16 + lr;
          float xp[2][4][4];
#pragma unroll
          for (int m = 0; m < 2; ++m)
#pragma unroll
            for (int i = 0; i < 4; ++i) {
              const int b = mh * 32 + m * 16 + lq * 4 + i;
#pragma unroll
              for (int gt = 0; gt < 4; ++gt)
                xp[m][gt][i] = ring_loadf(xpre + (b * 2048 + gt * 512 + ucol) * 4);
            }
          const char* ahi = ws + OFF_H0 + ((t0 - 1) & 1) * HB_SLOT;
          i32x4 areg[16];
#pragma unroll
          for (int kc = 0; kc < 4; ++kc)
#pragma unroll
            for (int it = 0; it < 4; ++it) {
              const int idx = it * 2048 + tid * 8, row = idx >> 7, col = idx & 127;
              areg[kc * 4 + it] = ring_load16(ahi + (row * 512 + kc * 128 + col) * 2);
            }
          const float kk = ktabp[t0 * 1024 + ucol];
          float cold[2][4];
#pragma unroll
          for (int m = 0; m < 2; ++m)
#pragma unroll
            for (int i = 0; i < 4; ++i) {
              const int b = mh * 32 + m * 16 + lq * 4 + i;
              cold[m][i] = *(const float*)(c0p + (b * 512 + ucol) * 4);
            }
          f32x4 acc[2][4] = {};
#pragma unroll
          for (int kc = 0; kc < 4; ++kc) {
            __syncthreads();
#pragma unroll
            for (int it = 0; it < 4; ++it) {
              const int idx = it * 2048 + tid * 8, row = idx >> 7, col = idx & 127;
              *(i32x4*)(Al + (((row * 128 + col) * 2) ^ ((row & 7) << 4))) = areg[kc * 4 + it];
            }
            __syncthreads();
#pragma unroll
            for (int ks = 0; ks < 4; ++ks) {
              bf16x8 af[2];
#pragma unroll
              for (int m = 0; m < 2; ++m) {
                const int b = mh * 32 + m * 16 + lr;
                af[m] = lds_frag(Al + (((b * 128 + ks * 32 + lq * 8) * 2) ^ ((b & 7) << 4)));
              }
#pragma unroll
              for (int gt = 0; gt < 4; ++gt) {
                const int j = gt * 32 + uf * 16 + lr;
                const bf16x8 bf = lds_frag(Wl + (((j * 512 + kc * 128 + ks * 32 + lq * 8) * 2) ^ ((j & 7) << 4)));
                acc[0][gt] = mfma16(af[0], bf, acc[0][gt]);
                acc[1][gt] = mfma16(af[1], bf, acc[1][gt]);
              }
            }
          }
          // epilogue: compute, c/out plain; h -> LDS stage -> coalesced NT store
          __syncthreads();                       // Al now free for staging
          unsigned short* Hs = (unsigned short*)Al;   // [64 b][32 u_local]
#pragma unroll
          for (int m = 0; m < 2; ++m)
#pragma unroll
            for (int i = 0; i < 4; ++i) {
              const int b = mh * 32 + m * 16 + lq * 4 + i;
              const float gi = acc[m][0][i] + xp[m][0][i];
              const float gf = acc[m][1][i] + xp[m][1][i];
              const float gz = acc[m][2][i] + xp[m][2][i];
              const float go = acc[m][3][i] + xp[m][3][i];
              const float itg = sigm(gi) * kk;
              const float ftg = sigm(gf + 1.0f - kk);
              const float gtg = tanhfast(gz) * kk;
              const float otg = sigm(go) * kk;
              const float cn = ftg * cold[m][i] + itg * gtg;
              const float hn = otg * tanhfast(cn);
              *(float*)(c0p + (b * 512 + ucol) * 4) = cn;
              Hs[b * 32 + uf * 16 + lr] = f2bf(hn);
              if (t0 == 1023) {
                out[33554432 + b * 512 + ucol] = hn;
                out[33554432 + 65536 + b * 512 + ucol] = cn;
              }
            }
          __syncthreads();
          {
            const int r = tid >> 2, seg = tid & 3;       // 64 rows x 4 segs of 16B
            i32x4 v = *(const i32x4*)(Hs + r * 32 + seg * 8);
            ring_store16(h0bw + (r * 512 + grp * 32 + seg * 8) * 2, v);
          }
        }
      }
    } else if (role == 1) {
      // ================ G1: h1 for t1 = q-2 (K=1024: h0[t1] || h1[t1-1]) ================
      if (q >= 2 && q <= 1025) {
        const int t1 = q - 2;
        char* c1p = wsw + OFF_C1;
        char* h1bw = wsw + OFF_H1 + (t1 & 1) * HB_SLOT;   // block-major layout

        if (t1 <= TPREC) {
          // ---- exact fp32 path (scalar stores, new h1b layout) ----
          const int rp = tid >> 4, bq = tid & 15;
          const int gate = rp >> 2;
          const int uoff0 = (rp & 3) * 4;
          const float* wx4 = Wxh_w + 1048576 + (size_t)(gate * 512 + grp * 16 + uoff0) * 512;
          const float* wh4 = Whh_w + 1048576 + (size_t)(gate * 512 + grp * 16 + uoff0) * 512;
          const char* s0f = ws + OFF_H0F + (t1 & 1) * HF_SLOT;
          const char* s1f = ws + OFF_H1F + ((t1 - 1) & 1) * HF_SLOT;
          f32x4 acc4[4] = {};
          for (int kc = 0; kc < 16; ++kc) {
            const char* hsrc = (kc < 8) ? s0f : s1f;
            const int k0 = (kc & 7) * 64;
            const float* wsel = (kc < 8) ? (wx4 + k0) : (wh4 + k0);
            __syncthreads();
            for (int i = 0; i < 4; ++i) {
              int qi = tid + 256 * i, k = qi >> 4, b4 = qi & 15;
              i32x4 v = ring_load16(hsrc + ((k0 + k) * 64 + b4 * 4) * 4);
              *(i32x4*)(Alf + k * 64 + b4 * 4) = v;
            }
            __syncthreads();
            for (int kb = 0; kb < 16; ++kb) {
              f32x4 w4[4];
#pragma unroll
              for (int r = 0; r < 4; ++r) w4[r] = *(const f32x4*)(wsel + r * 512 + kb * 4);
#pragma unroll
              for (int ks = 0; ks < 4; ++ks) {
                f32x4 hv = *(const f32x4*)(Alf + (kb * 4 + ks) * 64 + bq * 4);
#pragma unroll
                for (int r = 0; r < 4; ++r) acc4[r] += w4[r][ks] * hv;
              }
            }
          }
          char* h1fw = wsw + OFF_H1F + (t1 & 1) * HF_SLOT;
          __syncthreads();
#pragma unroll
          for (int r = 0; r < 4; ++r)
            *(f32x4*)(Alf + (rp * 4 + r) * 64 + bq * 4) = acc4[r];
          __syncthreads();
          for (int i = 0; i < 4; ++i) {
            int e = tid + 256 * i;
            int u = e >> 6, b = e & 63;
            int ucol = grp * 16 + u;
            float g4[4];
#pragma unroll
            for (int gt = 0; gt < 4; ++gt)
              g4[gt] = Alf[(gt * 16 + u) * 64 + b] + bias1[gt * 512 + ucol];
            const float kk = ktabp[t1 * 1024 + 512 + ucol];
            const float cold = *(const float*)(c1p + (b * 512 + ucol) * 4);
            const float itg = sigm(g4[0]) * kk;
            const float ftg = sigm(g4[1] + 1.0f - kk);
            const float gtg = tanhfast(g4[2]) * kk;
            const float otg = sigm(g4[3]) * kk;
            const float cn = ftg * cold + itg * gtg;
            const float hn = otg * tanhfast(cn);
            *(float*)(c1p + (b * 512 + ucol) * 4) = cn;
            ring_store_u16(h1bw + grp * 2048 + (b * 16 + u) * 2, (unsigned)f2bf(hn));
            ring_storef(h1fw + (ucol * 64 + b) * 4, hn);
            out[t1 * 32768 + b * 512 + ucol] = hn;
          }
        } else {
          // ---- bf16 MFMA fast path (LDS-staged A; h1b reads in block-major) ----
          const int ucol = grp * 16 + lr;
          float bs[4];
#pragma unroll
          for (int gt = 0; gt < 4; ++gt) bs[gt] = bias1[gt * 512 + ucol];
          const float kk = ktabp[t1 * 1024 + 512 + ucol];
          const char* s0 = ws + OFF_H0 + (t1 & 1) * HB_SLOT;
          const char* s1 = ws + OFF_H1 + ((t1 - 1) & 1) * HB_SLOT;
          i32x4 areg[32];
#pragma unroll
          for (int kc = 0; kc < 8; ++kc) {
            const int kb = (kc & 3) * 128;
#pragma unroll
            for (int it = 0; it < 4; ++it) {
              const int idx = it * 2048 + tid * 8, row = idx >> 7, col = idx & 127;
              if (kc < 4) {
                areg[kc * 4 + it] = ring_load16(s0 + (row * 512 + kb + col) * 2);
              } else {
                const int U = kb + col;   // unit index 0..511; col%8==0 so 16B stays in-group
                areg[kc * 4 + it] = ring_load16(s1 + (U >> 4) * 2048 + (row * 16 + (U & 15)) * 2);
              }
            }
          }
          float cold[4];
#pragma unroll
          for (int i = 0; i < 4; ++i) {
            const int b = wv * 16 + lq * 4 + i;
            cold[i] = *(const float*)(c1p + (b * 512 + ucol) * 4);
          }
          f32x4 acc[4] = {};
#pragma unroll
          for (int kc = 0; kc < 8; ++kc) {
            __syncthreads();
#pragma unroll
            for (int it = 0; it < 4; ++it) {
              const int idx = it * 2048 + tid * 8, row = idx >> 7, col = idx & 127;
              *(i32x4*)(Al + (((row * 128 + col) * 2) ^ ((row & 7) << 4))) = areg[kc * 4 + it];
            }
            __syncthreads();
#pragma unroll
            for (int ks = 0; ks < 4; ++ks) {
              const int b = wv * 16 + lr;
              const bf16x8 af = lds_frag(Al + (((b * 128 + ks * 32 + lq * 8) * 2) ^ ((b & 7) << 4)));
#pragma unroll
              for (int gt = 0; gt < 4; ++gt) {
                const int j = gt * 16 + lr;
                const bf16x8 bf = lds_frag(Wl + (((j * 1024 + kc * 128 + ks * 32 + lq * 8) * 2) ^ ((j & 7) << 4)));
                acc[gt] = mfma16(af, bf, acc[gt]);
              }
            }
          }
          // epilogue: compute, c/out plain; h1 -> LDS stage -> contiguous 2KB NT store
          __syncthreads();                       // Al free
          unsigned short* Hs = (unsigned short*)Al;   // [64 b][16 u_local]
#pragma unroll
          for (int i = 0; i < 4; ++i) {
            const int b = wv * 16 + lq * 4 + i;
            const float gi = acc[0][i] + bs[0];
            const float gf = acc[1][i] + bs[1];
            const float gz = acc[2][i] + bs[2];
            const float go = acc[3][i] + bs[3];
            const float itg = sigm(gi) * kk;
            const float ftg = sigm(gf + 1.0f - kk);
            const float gtg = tanhfast(gz) * kk;
            const float otg = sigm(go) * kk;
            const float cn = ftg * cold[i] + itg * gtg;
            const float hn = otg * tanhfast(cn);
            *(float*)(c1p + (b * 512 + ucol) * 4) = cn;
            Hs[b * 16 + lr] = f2bf(hn);
            out[t1 * 32768 + b * 512 + ucol] = hn;
            if (t1 == 1023) {
              out[33554432 + 32768 + b * 512 + ucol] = hn;
              out[33554432 + 65536 + 32768 + b * 512 + ucol] = cn;
            }
          }
          __syncthreads();
          if (tid < 128) {
            i32x4 v = *(const i32x4*)(Hs + tid * 8);
            ring_store16(h1bw + grp * 2048 + tid * 16, v);
          }
        }
      }
    } else {
      // ================ XP: Xpre[q] = x[q] @ Wxh0^T + b0 ================
      if (q <= 1023) {
        const float* xs = xin + (size_t)q * 32768;
        char* xw = wsw + OFF_XPRE + (q & 1) * XP_SLOT;

        if (q <= TPREC) {
          // ---- exact fp32 path (scalar stores, 9 phases only) ----
          const int rp = tid >> 4, bq = tid & 15;
          const int n0 = grp * 128 + rp * 8;
          const float* w8 = Wxh_w + (size_t)n0 * 512;
          f32x4 acc8[8] = {};
          for (int kc = 0; kc < 8; ++kc) {
            __syncthreads();
            for (int i = 0; i < 4; ++i) {
              int qi = tid + 256 * i, b = qi >> 4, k4 = qi & 15;
              f32x4 v = *(const f32x4*)(xs + b * 512 + kc * 64 + k4 * 4);
#pragma unroll
              for (int j = 0; j < 4; ++j) Alf[(k4 * 4 + j) * 64 + b] = v[j];
            }
            __syncthreads();
            for (int kb = 0; kb < 16; ++kb) {
              f32x4 w4[8];
#pragma unroll
              for (int r = 0; r < 8; ++r) w4[r] = *(const f32x4*)(w8 + r * 512 + kc * 64 + kb * 4);
#pragma unroll
              for (int ks = 0; ks < 4; ++ks) {
                f32x4 hv = *(const f32x4*)(Alf + (kb * 4 + ks) * 64 + bq * 4);
#pragma unroll
                for (int r = 0; r < 8; ++r) acc8[r] += w4[r][ks] * hv;
              }
            }
          }
#pragma unroll
          for (int r = 0; r < 8; ++r) {
            const int n = n0 + r;
            const float bv = bias0[n];
#pragma unroll
            for (int j = 0; j < 4; ++j)
              ring_storef(xw + ((bq * 4 + j) * 2048 + n) * 4, acc8[r][j] + bv);
          }
        } else {
          // ---- bf16 MFMA fast path; Xpre -> LDS stage -> coalesced 512B-row NT stores ----
          float b0v[2];
#pragma unroll
          for (int nf = 0; nf < 2; ++nf) b0v[nf] = bias0[grp * 128 + wv * 32 + nf * 16 + lr];
          f32x4 xr[4][4][2];
#pragma unroll
          for (int kc = 0; kc < 4; ++kc)
#pragma unroll
            for (int it = 0; it < 4; ++it) {
              const int idx = it * 2048 + tid * 8, row = idx >> 7, col = idx & 127;
              const float* p = xs + row * 512 + kc * 128 + col;
              xr[kc][it][0] = *(const f32x4*)p;
              xr[kc][it][1] = *(const f32x4*)(p + 4);
            }
          f32x4 acc[4][2] = {};
#pragma unroll
          for (int kc = 0; kc < 4; ++kc) {
            __syncthreads();
#pragma unroll
            for (int it = 0; it < 4; ++it) {
              const int idx = it * 2048 + tid * 8, row = idx >> 7, col = idx & 127;
              i32x4 v;
#pragma unroll
              for (int w2 = 0; w2 < 4; ++w2) {
                const float x0 = xr[kc][it][w2 >> 1][(w2 & 1) * 2 + 0];
                const float x1 = xr[kc][it][w2 >> 1][(w2 & 1) * 2 + 1];
                v[w2] = (int)((unsigned)f2bf(x0) | ((unsigned)f2bf(x1) << 16));
              }
              *(i32x4*)(Al + (((row * 128 + col) * 2) ^ ((row & 7) << 4))) = v;
            }
            __syncthreads();
#pragma unroll
            for (int ks = 0; ks < 4; ++ks) {
              bf16x8 af[4];
#pragma unroll
              for (int m = 0; m < 4; ++m) {
                const int b = m * 16 + lr;
                af[m] = lds_frag(Al + (((b * 128 + ks * 32 + lq * 8) * 2) ^ ((b & 7) << 4)));
              }
#pragma unroll
              for (int nf = 0; nf < 2; ++nf) {
                const int j = wv * 32 + nf * 16 + lr;
                const bf16x8 bf = lds_frag(Wl + (((j * 512 + kc * 128 + ks * 32 + lq * 8) * 2) ^ ((j & 7) << 4)));
#pragma unroll
                for (int m = 0; m < 4; ++m) acc[m][nf] = mfma16(af[m], bf, acc[m][nf]);
              }
            }
          }
          // stage+store in two b-halves (Al = 16KB = [32 b][128 n] f32)
          __syncthreads();                       // Al free
#pragma unroll
          for (int h = 0; h < 2; ++h) {
#pragma unroll
            for (int m = 2 * h; m < 2 * h + 2; ++m)
#pragma unroll
              for (int nf = 0; nf < 2; ++nf)
#pragma unroll
                for (int i = 0; i < 4; ++i) {
                  const int b = m * 16 + lq * 4 + i;
                  Alf[(b - 32 * h) * 128 + wv * 32 + nf * 16 + lr] = acc[m][nf][i] + b0v[nf];
                }
            __syncthreads();
#pragma unroll
            for (int j = 0; j < 4; ++j) {
              const int off = (j * 256 + tid) * 4;       // float index in [0,4096)
              const int rr = off >> 7, cc = off & 127;
              i32x4 v = *(const i32x4*)(Alf + off);
              ring_store16(xw + ((32 * h + rr) * 2048 + grp * 128 + cc) * 4, v);
            }
            __syncthreads();
          }
        }
      }
    }

    // -------- device-wide phase barrier: two-level, aggregated (R6 verbatim) --------
    __syncthreads();
    {
      const unsigned tgt = (unsigned)(q + 1);
      if (bid == 63) {
        if (tid < 64) {
          while (true) {
            const unsigned v = (tid < 63) ? flag_load(arr + tid * 16) : tgt;
            if (__ballot((int)(v >= tgt)) == ~0ull) break;
            __builtin_amdgcn_s_sleep(2);
          }
          if (tid == 0) flag_store(epoch, tgt);
        }
      } else {
        if (tid == 0) {
          flag_store(arr + bid * 16, tgt);
          while (flag_load(epoch) < tgt) __builtin_amdgcn_s_sleep(2);
        }
      }
    }
    __syncthreads();
  }
}

extern "C" void kernel_launch(void* const* d_in, const int* in_sizes, int n_in,
                              void* d_out, int out_size, void* d_ws, size_t ws_size,
                              hipStream_t stream) {
  (void)in_sizes; (void)n_in; (void)out_size; (void)ws_size;
  const float* inputs = (const float*)d_in[0];
  const float* times  = (const float*)d_in[1];
  const float* Wxh_w  = (const float*)d_in[2];
  const float* Wxh_b  = (const float*)d_in[3];
  const float* Whh_w  = (const float*)d_in[4];
  const float* tau    = (const float*)d_in[5];
  const float* s_p    = (const float*)d_in[6];
  unsigned char* ws = (unsigned char*)d_ws;
  float* out = (float*)d_out;

  hipMemsetAsync(ws + OFF_ARR, 0, 4096, stream);                // arrival flags + epoch = 0
  hipMemsetAsync(ws + OFF_H0 + HB_SLOT, 0, HB_SLOT, stream);
  hipMemsetAsync(ws + OFF_H1 + HB_SLOT, 0, HB_SLOT, stream);
  hipMemsetAsync(ws + OFF_H0F + HF_SLOT, 0, HF_SLOT, stream);
  hipMemsetAsync(ws + OFF_H1F + HF_SLOT, 0, HF_SLOT, stream);
  hipMemsetAsync(ws + OFF_C0, 0, 131072, stream);
  hipMemsetAsync(ws + OFF_C1, 0, 131072, stream);

  plstm_prep<<<8192, 256, 0, stream>>>(Wxh_w, Whh_w, times, tau, s_p, ws);
  plstm_main<<<NBLK, 256, 0, stream>>>(inputs, Wxh_b, Wxh_w, Whh_w, out, ws);
}

// Round 17
// 12623.886 us; speedup vs baseline: 1.6921x; 1.6921x over previous
//
#include <hip/hip_runtime.h>

// PhasedLSTM: S=1024, B=64, H=512, L=2. ONE KERNEL PER PIPELINE PHASE (R6's
// proven compute transplanted verbatim; barrier -> kernel boundary).
// Kernel q (q=0..1025): XP blocks compute Xpre[q]=x[q]@Wxh0^T+b0 ; G0 blocks
// compute h0[q-1] ; G1 blocks compute h1[q-2]. All inputs of kernel q were
// produced by kernel q-1, so same-stream launch ordering IS the sync (incl.
// cross-XCD). No persistent grid, no spin barriers, no cache-scope asm.
// t<=8 phases: exact fp32 VALU path (time-gate k=2phi/RHO reaches -40; gate
// error is amplified ~k^3 -> bf16 insufficient). t>=9: k<=1 -> bf16 MFMA path.
// FINAL: best measured config (12.76 ms). Persistent-kernel alternatives
// measured 21-49 ms across 5 sync/coherence mechanisms; per-phase variants
// (fused roles, 128-block, direct-global operands) all regressed vs this.

#define TPREC 8

// d_ws byte offsets (R6 layout, OFF_ARR unused)
#define OFF_H0    4096            // 2 slots x [64][512] bf16
#define OFF_H1    266240
#define OFF_H0F   528384          // 2 slots x [512 u][64 b] f32 (early-phase operand)
#define OFF_H1F   1052672
#define OFF_C0    1576960         // [64 b][512 u] f32 cell state
#define OFF_C1    1708032
#define OFF_XPRE  1839104         // 2 slots x [64 b][2048 n] f32
#define OFF_KTAB  2887680         // [1024 t][2 l][512 u] f32
#define OFF_W0    7081984         // 16 blk x [128][512]  bf16 (gate-grouped Whh0)
#define OFF_W1    9179136         // 32 blk x [64][1024]  bf16 ([Wxh1 ; Whh1])
#define OFF_WX    13373440        // 16 blk x [128][512]  bf16 (Wxh0)

#define HB_SLOT   65536
#define HF_SLOT   131072
#define XP_SLOT   524288

typedef float  f32x4  __attribute__((ext_vector_type(4)));
typedef int    i32x4  __attribute__((ext_vector_type(4)));
typedef __bf16 bf16x8 __attribute__((ext_vector_type(8)));

static __device__ __forceinline__ unsigned short f2bf(float f) {
  unsigned u = __builtin_bit_cast(unsigned, f);
  u += 0x7FFFu + ((u >> 16) & 1u);        // RNE
  return (unsigned short)(u >> 16);
}
static __device__ __forceinline__ float sigm(float x) { return 1.0f / (1.0f + __expf(-x)); }
static __device__ __forceinline__ float tanhfast(float x) { return 1.0f - 2.0f / (__expf(2.0f * x) + 1.0f); }

// Cross-kernel ring ops are PLAIN cached accesses: the kernel boundary provides
// ordering + coherence (same-stream dependent launches).
static __device__ __forceinline__ i32x4 ring_load16(const void* p) {
  return *(const i32x4*)p;
}
static __device__ __forceinline__ float ring_loadf(const void* p) {
  return *(const float*)p;
}
static __device__ __forceinline__ void ring_storef(void* p, float v) {
  *(float*)p = v;
}
static __device__ __forceinline__ void ring_store_u16(void* p, unsigned v) {
  *(unsigned short*)p = (unsigned short)v;
}

static __device__ __forceinline__ f32x4 mfma16(bf16x8 a, bf16x8 b, f32x4 c) {
  return __builtin_amdgcn_mfma_f32_16x16x32_bf16(a, b, c, 0, 0, 0);
}
static __device__ __forceinline__ bf16x8 lds_frag(const char* p) {
  return __builtin_bit_cast(bf16x8, *(const i32x4*)p);
}

// ---------------- prep: bf16 weight relayout + time-gate table ----------------
__global__ void plstm_prep(const float* __restrict__ Wxh_w, const float* __restrict__ Whh_w,
                           const float* __restrict__ times, const float* __restrict__ tau,
                           const float* __restrict__ s_p, unsigned char* __restrict__ ws) {
  const int idx = blockIdx.x * 256 + threadIdx.x;
  const int stride = gridDim.x * 256;
  for (int e = idx; e < 1048576; e += stride) {
    int g = e >> 16, j = (e >> 9) & 127, k = e & 511;
    int gate = j >> 5, u = g * 32 + (j & 31);
    ((unsigned short*)(ws + OFF_W0))[e] = f2bf(Whh_w[(gate * 512 + u) * 512 + k]);
  }
  for (int e = idx; e < 2097152; e += stride) {
    int g = e >> 16, j = (e >> 10) & 63, k = e & 1023;
    int gate = j >> 4, row = gate * 512 + g * 16 + (j & 15);
    float v = (k < 512) ? Wxh_w[1048576 + row * 512 + k] : Whh_w[1048576 + row * 512 + (k - 512)];
    ((unsigned short*)(ws + OFF_W1))[e] = f2bf(v);
  }
  for (int e = idx; e < 1048576; e += stride) {
    int g = e >> 16, j = (e >> 9) & 127, k = e & 511;
    ((unsigned short*)(ws + OFF_WX))[e] = f2bf(Wxh_w[(g * 128 + j) * 512 + k]);
  }
  for (int e = idx; e < 1048576; e += stride) {
    int t = e >> 10, r = e & 1023, l = r >> 9, u = r & 511;
    float phi = fmodf(times[t] - s_p[l * 512 + u], tau[l * 512 + u]) / tau[l * 512 + u];
    float kv;
    if (phi < 0.025f)      kv = phi * 40.0f;
    else if (phi < 0.05f)  kv = 2.0f - phi * 40.0f;
    else                   kv = 0.001f * phi;
    ((float*)(ws + OFF_KTAB))[e] = kv;
  }
}

// ---------------- per-phase kernel (q as argument) ----------------
__global__ void __launch_bounds__(256, 1)
plstm_step(const float* __restrict__ xin, const float* __restrict__ bias,
           const float* __restrict__ Wxh_w, const float* __restrict__ Whh_w,
           float* __restrict__ out, unsigned char* __restrict__ wsu, int q) {
  __shared__ char Wl[131072];   // bf16 weight slice (reloaded each launch, L2-hot)
  __shared__ char Al[16384];    // A staging / f32 redistribution

  const char* ws = (const char*)wsu;
  char* wsw = (char*)wsu;
  const int bid = blockIdx.x, tid = threadIdx.x;
  const int lane = tid & 63, wv = tid >> 6;
  const int lq = lane >> 4, lr = lane & 15;
  const int role = (bid < 16) ? 0 : (bid < 48) ? 1 : 2;
  const int grp = (role == 0) ? bid : (role == 1) ? bid - 16 : bid - 48;

  // activity windows: G0: 1<=q<=1024 ; G1: 2<=q<=1025 ; XP: q<=1023
  if (role == 0 && (q < 1 || q > 1024)) return;
  if (role == 1 && (q < 2 || q > 1025)) return;
  if (role == 2 && q > 1023) return;

  const float* ktabp = (const float*)(ws + OFF_KTAB);
  const float* bias0 = bias;
  const float* bias1 = bias + 2048;
  float* Alf = (float*)Al;

  // --- bf16 W slice -> LDS (swizzle: byte ^= (row&7)<<4) ---
  {
    const char* wsrc = ws +
      ((role == 0) ? (OFF_W0 + grp * 131072) : (role == 1) ? (OFF_W1 + grp * 131072)
                                             : (OFF_WX + grp * 131072));
    const int kshift = (role == 1) ? 10 : 9;
    for (int e = tid * 8; e < 65536; e += 2048) {
      i32x4 v = *(const i32x4*)(wsrc + e * 2);
      int row = e >> kshift;
      *(i32x4*)(Wl + ((e * 2) ^ ((row & 7) << 4))) = v;
    }
    __syncthreads();
  }

  if (role == 0) {
    // ================ G0: h0 for t0 = q-1 ================
    {
      const int t0 = q - 1;
      const char* xpre = ws + OFF_XPRE + (t0 & 1) * XP_SLOT;
      char* c0p = wsw + OFF_C0;
      char* h0bw = wsw + OFF_H0 + (t0 & 1) * HB_SLOT;

      if (t0 <= TPREC) {
        // ---- exact fp32 path ----
        const int rp = tid >> 4, bq = tid & 15;
        const int gate = rp >> 2;
        const int u0 = grp * 32 + (rp & 3) * 8;
        const float* w8 = Whh_w + (size_t)(gate * 512 + u0) * 512;
        const char* hsrc = ws + OFF_H0F + ((t0 - 1) & 1) * HF_SLOT;
        f32x4 acc8[8] = {};
        for (int kc = 0; kc < 8; ++kc) {
          __syncthreads();
          for (int i = 0; i < 4; ++i) {
            int qi = tid + 256 * i, k = qi >> 4, b4 = qi & 15;
            i32x4 v = ring_load16(hsrc + ((kc * 64 + k) * 64 + b4 * 4) * 4);
            *(i32x4*)(Alf + k * 64 + b4 * 4) = v;
          }
          __syncthreads();
          for (int kb = 0; kb < 16; ++kb) {
            f32x4 w4[8];
#pragma unroll
            for (int r = 0; r < 8; ++r) w4[r] = *(const f32x4*)(w8 + r * 512 + kc * 64 + kb * 4);
#pragma unroll
            for (int ks = 0; ks < 4; ++ks) {
              f32x4 hv = *(const f32x4*)(Alf + (kb * 4 + ks) * 64 + bq * 4);
#pragma unroll
              for (int r = 0; r < 8; ++r) acc8[r] += w4[r][ks] * hv;
            }
          }
        }
        char* h0fw = wsw + OFF_H0F + (t0 & 1) * HF_SLOT;
        for (int ph = 0; ph < 2; ++ph) {
          __syncthreads();
          if ((bq >> 3) == ph) {
#pragma unroll
            for (int r = 0; r < 8; ++r)
              *(f32x4*)(Alf + (rp * 8 + r) * 32 + (bq & 7) * 4) = acc8[r];
          }
          __syncthreads();
          for (int i = 0; i < 4; ++i) {
            int e = tid + 256 * i;
            int u = e >> 5, b32 = e & 31, b = ph * 32 + b32;
            int ucol = grp * 32 + u;
            float g4[4];
#pragma unroll
            for (int gt = 0; gt < 4; ++gt)
              g4[gt] = Alf[(gt * 32 + u) * 32 + b32]
                     + ring_loadf(xpre + (b * 2048 + gt * 512 + ucol) * 4);
            const float kk = ktabp[t0 * 1024 + ucol];
            const float cold = *(const float*)(c0p + (b * 512 + ucol) * 4);
            const float itg = sigm(g4[0]) * kk;
            const float ftg = sigm(g4[1] + 1.0f - kk);
            const float gtg = tanhfast(g4[2]) * kk;
            const float otg = sigm(g4[3]) * kk;
            const float cn = ftg * cold + itg * gtg;
            const float hn = otg * tanhfast(cn);
            *(float*)(c0p + (b * 512 + ucol) * 4) = cn;
            ring_store_u16(h0bw + (b * 512 + ucol) * 2, (unsigned)f2bf(hn));
            ring_storef(h0fw + (ucol * 64 + b) * 4, hn);
          }
        }
      } else {
        // ---- bf16 MFMA fast path (LDS-staged A) ----
        const int uf = wv >> 1, mh = wv & 1;
        const int ucol = grp * 32 + uf * 16 + lr;
        float xp[2][4][4];
#pragma unroll
        for (int m = 0; m < 2; ++m)
#pragma unroll
          for (int i = 0; i < 4; ++i) {
            const int b = mh * 32 + m * 16 + lq * 4 + i;
#pragma unroll
            for (int gt = 0; gt < 4; ++gt)
              xp[m][gt][i] = ring_loadf(xpre + (b * 2048 + gt * 512 + ucol) * 4);
          }
        const char* ahi = ws + OFF_H0 + ((t0 - 1) & 1) * HB_SLOT;
        i32x4 areg[16];
#pragma unroll
        for (int kc = 0; kc < 4; ++kc)
#pragma unroll
          for (int it = 0; it < 4; ++it) {
            const int idx = it * 2048 + tid * 8, row = idx >> 7, col = idx & 127;
            areg[kc * 4 + it] = ring_load16(ahi + (row * 512 + kc * 128 + col) * 2);
          }
        const float kk = ktabp[t0 * 1024 + ucol];
        float cold[2][4];
#pragma unroll
        for (int m = 0; m < 2; ++m)
#pragma unroll
          for (int i = 0; i < 4; ++i) {
            const int b = mh * 32 + m * 16 + lq * 4 + i;
            cold[m][i] = *(const float*)(c0p + (b * 512 + ucol) * 4);
          }
        char* c0pw = wsw + OFF_C0;
        f32x4 acc[2][4] = {};
#pragma unroll
        for (int kc = 0; kc < 4; ++kc) {
          __syncthreads();
#pragma unroll
          for (int it = 0; it < 4; ++it) {
            const int idx = it * 2048 + tid * 8, row = idx >> 7, col = idx & 127;
            *(i32x4*)(Al + (((row * 128 + col) * 2) ^ ((row & 7) << 4))) = areg[kc * 4 + it];
          }
          __syncthreads();
#pragma unroll
          for (int ks = 0; ks < 4; ++ks) {
            bf16x8 af[2];
#pragma unroll
            for (int m = 0; m < 2; ++m) {
              const int b = mh * 32 + m * 16 + lr;
              af[m] = lds_frag(Al + (((b * 128 + ks * 32 + lq * 8) * 2) ^ ((b & 7) << 4)));
            }
#pragma unroll
            for (int gt = 0; gt < 4; ++gt) {
              const int j = gt * 32 + uf * 16 + lr;
              const bf16x8 bf = lds_frag(Wl + (((j * 512 + kc * 128 + ks * 32 + lq * 8) * 2) ^ ((j & 7) << 4)));
              acc[0][gt] = mfma16(af[0], bf, acc[0][gt]);
              acc[1][gt] = mfma16(af[1], bf, acc[1][gt]);
            }
          }
        }
#pragma unroll
        for (int m = 0; m < 2; ++m)
#pragma unroll
          for (int i = 0; i < 4; ++i) {
            const int b = mh * 32 + m * 16 + lq * 4 + i;
            const float gi = acc[m][0][i] + xp[m][0][i];
            const float gf = acc[m][1][i] + xp[m][1][i];
            const float gz = acc[m][2][i] + xp[m][2][i];
            const float go = acc[m][3][i] + xp[m][3][i];
            const float itg = sigm(gi) * kk;
            const float ftg = sigm(gf + 1.0f - kk);
            const float gtg = tanhfast(gz) * kk;
            const float otg = sigm(go) * kk;
            const float cn = ftg * cold[m][i] + itg * gtg;
            const float hn = otg * tanhfast(cn);
            *(float*)(c0pw + (b * 512 + ucol) * 4) = cn;
            ring_store_u16(h0bw + (b * 512 + ucol) * 2, (unsigned)f2bf(hn));
            if (t0 == 1023) {
              out[33554432 + b * 512 + ucol] = hn;
              out[33554432 + 65536 + b * 512 + ucol] = cn;
            }
          }
      }
    }
  } else if (role == 1) {
    // ================ G1: h1 for t1 = q-2 (K=1024: h0[t1] || h1[t1-1]) ================
    {
      const int t1 = q - 2;
      char* c1p = wsw + OFF_C1;
      char* h1bw = wsw + OFF_H1 + (t1 & 1) * HB_SLOT;

      if (t1 <= TPREC) {
        // ---- exact fp32 path ----
        const int rp = tid >> 4, bq = tid & 15;
        const int gate = rp >> 2;
        const int uoff0 = (rp & 3) * 4;
        const float* wx4 = Wxh_w + 1048576 + (size_t)(gate * 512 + grp * 16 + uoff0) * 512;
        const float* wh4 = Whh_w + 1048576 + (size_t)(gate * 512 + grp * 16 + uoff0) * 512;
        const char* s0f = ws + OFF_H0F + (t1 & 1) * HF_SLOT;
        const char* s1f = ws + OFF_H1F + ((t1 - 1) & 1) * HF_SLOT;
        f32x4 acc4[4] = {};
        for (int kc = 0; kc < 16; ++kc) {
          const char* hsrc = (kc < 8) ? s0f : s1f;
          const int k0 = (kc & 7) * 64;
          const float* wsel = (kc < 8) ? (wx4 + k0) : (wh4 + k0);
          __syncthreads();
          for (int i = 0; i < 4; ++i) {
            int qi = tid + 256 * i, k = qi >> 4, b4 = qi & 15;
            i32x4 v = ring_load16(hsrc + ((k0 + k) * 64 + b4 * 4) * 4);
            *(i32x4*)(Alf + k * 64 + b4 * 4) = v;
          }
          __syncthreads();
          for (int kb = 0; kb < 16; ++kb) {
            f32x4 w4[4];
#pragma unroll
            for (int r = 0; r < 4; ++r) w4[r] = *(const f32x4*)(wsel + r * 512 + kb * 4);
#pragma unroll
            for (int ks = 0; ks < 4; ++ks) {
              f32x4 hv = *(const f32x4*)(Alf + (kb * 4 + ks) * 64 + bq * 4);
#pragma unroll
              for (int r = 0; r < 4; ++r) acc4[r] += w4[r][ks] * hv;
            }
          }
        }
        char* h1fw = wsw + OFF_H1F + (t1 & 1) * HF_SLOT;
        __syncthreads();
#pragma unroll
        for (int r = 0; r < 4; ++r)
          *(f32x4*)(Alf + (rp * 4 + r) * 64 + bq * 4) = acc4[r];
        __syncthreads();
        for (int i = 0; i < 4; ++i) {
          int e = tid + 256 * i;
          int u = e >> 6, b = e & 63;
          int ucol = grp * 16 + u;
          float g4[4];
#pragma unroll
          for (int gt = 0; gt < 4; ++gt)
            g4[gt] = Alf[(gt * 16 + u) * 64 + b] + bias1[gt * 512 + ucol];
          const float kk = ktabp[t1 * 1024 + 512 + ucol];
          const float cold = *(const float*)(c1p + (b * 512 + ucol) * 4);
          const float itg = sigm(g4[0]) * kk;
          const float ftg = sigm(g4[1] + 1.0f - kk);
          const float gtg = tanhfast(g4[2]) * kk;
          const float otg = sigm(g4[3]) * kk;
          const float cn = ftg * cold + itg * gtg;
          const float hn = otg * tanhfast(cn);
          *(float*)(c1p + (b * 512 + ucol) * 4) = cn;
          ring_store_u16(h1bw + (b * 512 + ucol) * 2, (unsigned)f2bf(hn));
          ring_storef(h1fw + (ucol * 64 + b) * 4, hn);
          out[t1 * 32768 + b * 512 + ucol] = hn;
        }
      } else {
        // ---- bf16 MFMA fast path (LDS-staged A) ----
        const int ucol = grp * 16 + lr;
        float bs[4];
#pragma unroll
        for (int gt = 0; gt < 4; ++gt) bs[gt] = bias1[gt * 512 + ucol];
        const float kk = ktabp[t1 * 1024 + 512 + ucol];
        const char* s0 = ws + OFF_H0 + (t1 & 1) * HB_SLOT;
        const char* s1 = ws + OFF_H1 + ((t1 - 1) & 1) * HB_SLOT;
        i32x4 areg[32];
#pragma unroll
        for (int kc = 0; kc < 8; ++kc) {
          const char* s = (kc < 4) ? s0 : s1;
          const int kb = (kc & 3) * 128;
#pragma unroll
          for (int it = 0; it < 4; ++it) {
            const int idx = it * 2048 + tid * 8, row = idx >> 7, col = idx & 127;
            areg[kc * 4 + it] = ring_load16(s + (row * 512 + kb + col) * 2);
          }
        }
        float cold[4];
#pragma unroll
        for (int i = 0; i < 4; ++i) {
          const int b = wv * 16 + lq * 4 + i;
          cold[i] = *(const float*)(c1p + (b * 512 + ucol) * 4);
        }
        f32x4 acc[4] = {};
#pragma unroll
        for (int kc = 0; kc < 8; ++kc) {
          __syncthreads();
#pragma unroll
          for (int it = 0; it < 4; ++it) {
            const int idx = it * 2048 + tid * 8, row = idx >> 7, col = idx & 127;
            *(i32x4*)(Al + (((row * 128 + col) * 2) ^ ((row & 7) << 4))) = areg[kc * 4 + it];
          }
          __syncthreads();
#pragma unroll
          for (int ks = 0; ks < 4; ++ks) {
            const int b = wv * 16 + lr;
            const bf16x8 af = lds_frag(Al + (((b * 128 + ks * 32 + lq * 8) * 2) ^ ((b & 7) << 4)));
#pragma unroll
            for (int gt = 0; gt < 4; ++gt) {
              const int j = gt * 16 + lr;
              const bf16x8 bf = lds_frag(Wl + (((j * 1024 + kc * 128 + ks * 32 + lq * 8) * 2) ^ ((j & 7) << 4)));
              acc[gt] = mfma16(af, bf, acc[gt]);
            }
          }
        }
#pragma unroll
        for (int i = 0; i < 4; ++i) {
          const int b = wv * 16 + lq * 4 + i;
          const float gi = acc[0][i] + bs[0];
          const float gf = acc[1][i] + bs[1];
          const float gz = acc[2][i] + bs[2];
          const float go = acc[3][i] + bs[3];
          const float itg = sigm(gi) * kk;
          const float ftg = sigm(gf + 1.0f - kk);
          const float gtg = tanhfast(gz) * kk;
          const float otg = sigm(go) * kk;
          const float cn = ftg * cold[i] + itg * gtg;
          const float hn = otg * tanhfast(cn);
          *(float*)(c1p + (b * 512 + ucol) * 4) = cn;
          ring_store_u16(h1bw + (b * 512 + ucol) * 2, (unsigned)f2bf(hn));
          out[t1 * 32768 + b * 512 + ucol] = hn;
          if (t1 == 1023) {
            out[33554432 + 32768 + b * 512 + ucol] = hn;
            out[33554432 + 65536 + 32768 + b * 512 + ucol] = cn;
          }
        }
      }
    }
  } else {
    // ================ XP: Xpre[q] = x[q] @ Wxh0^T + b0 ================
    {
      const float* xs = xin + (size_t)q * 32768;
      char* xw = wsw + OFF_XPRE + (q & 1) * XP_SLOT;

      if (q <= TPREC) {
        // ---- exact fp32 path ----
        const int rp = tid >> 4, bq = tid & 15;
        const int n0 = grp * 128 + rp * 8;
        const float* w8 = Wxh_w + (size_t)n0 * 512;
        f32x4 acc8[8] = {};
        for (int kc = 0; kc < 8; ++kc) {
          __syncthreads();
          for (int i = 0; i < 4; ++i) {
            int qi = tid + 256 * i, b = qi >> 4, k4 = qi & 15;
            f32x4 v = *(const f32x4*)(xs + b * 512 + kc * 64 + k4 * 4);
#pragma unroll
            for (int j = 0; j < 4; ++j) Alf[(k4 * 4 + j) * 64 + b] = v[j];
          }
          __syncthreads();
          for (int kb = 0; kb < 16; ++kb) {
            f32x4 w4[8];
#pragma unroll
            for (int r = 0; r < 8; ++r) w4[r] = *(const f32x4*)(w8 + r * 512 + kc * 64 + kb * 4);
#pragma unroll
            for (int ks = 0; ks < 4; ++ks) {
              f32x4 hv = *(const f32x4*)(Alf + (kb * 4 + ks) * 64 + bq * 4);
#pragma unroll
              for (int r = 0; r < 8; ++r) acc8[r] += w4[r][ks] * hv;
            }
          }
        }
#pragma unroll
        for (int r = 0; r < 8; ++r) {
          const int n = n0 + r;
          const float bv = bias0[n];
#pragma unroll
          for (int j = 0; j < 4; ++j)
            ring_storef(xw + ((bq * 4 + j) * 2048 + n) * 4, acc8[r][j] + bv);
        }
      } else {
        // ---- bf16 MFMA fast path (LDS-staged, single x read) ----
        float b0v[2];
#pragma unroll
        for (int nf = 0; nf < 2; ++nf) b0v[nf] = bias0[grp * 128 + wv * 32 + nf * 16 + lr];
        f32x4 xr[4][4][2];
#pragma unroll
        for (int kc = 0; kc < 4; ++kc)
#pragma unroll
          for (int it = 0; it < 4; ++it) {
            const int idx = it * 2048 + tid * 8, row = idx >> 7, col = idx & 127;
            const float* p = xs + row * 512 + kc * 128 + col;
            xr[kc][it][0] = *(const f32x4*)p;
            xr[kc][it][1] = *(const f32x4*)(p + 4);
          }
        f32x4 acc[4][2] = {};
#pragma unroll
        for (int kc = 0; kc < 4; ++kc) {
          __syncthreads();
#pragma unroll
          for (int it = 0; it < 4; ++it) {
            const int idx = it * 2048 + tid * 8, row = idx >> 7, col = idx & 127;
            i32x4 v;
#pragma unroll
            for (int w2 = 0; w2 < 4; ++w2) {
              const float x0 = xr[kc][it][w2 >> 1][(w2 & 1) * 2 + 0];
              const float x1 = xr[kc][it][w2 >> 1][(w2 & 1) * 2 + 1];
              v[w2] = (int)((unsigned)f2bf(x0) | ((unsigned)f2bf(x1) << 16));
            }
            *(i32x4*)(Al + (((row * 128 + col) * 2) ^ ((row & 7) << 4))) = v;
          }
          __syncthreads();
#pragma unroll
          for (int ks = 0; ks < 4; ++ks) {
            bf16x8 af[4];
#pragma unroll
            for (int m = 0; m < 4; ++m) {
              const int b = m * 16 + lr;
              af[m] = lds_frag(Al + (((b * 128 + ks * 32 + lq * 8) * 2) ^ ((b & 7) << 4)));
            }
#pragma unroll
            for (int nf = 0; nf < 2; ++nf) {
              const int j = wv * 32 + nf * 16 + lr;
              const bf16x8 bf = lds_frag(Wl + (((j * 512 + kc * 128 + ks * 32 + lq * 8) * 2) ^ ((j & 7) << 4)));
#pragma unroll
              for (int m = 0; m < 4; ++m) acc[m][nf] = mfma16(af[m], bf, acc[m][nf]);
            }
          }
        }
#pragma unroll
        for (int m = 0; m < 4; ++m)
#pragma unroll
          for (int nf = 0; nf < 2; ++nf)
#pragma unroll
            for (int i = 0; i < 4; ++i) {
              const int b = m * 16 + lq * 4 + i;
              const int n = grp * 128 + wv * 32 + nf * 16 + lr;
              ring_storef(xw + (b * 2048 + n) * 4, acc[m][nf][i] + b0v[nf]);
            }
      }
    }
  }
}

extern "C" void kernel_launch(void* const* d_in, const int* in_sizes, int n_in,
                              void* d_out, int out_size, void* d_ws, size_t ws_size,
                              hipStream_t stream) {
  (void)in_sizes; (void)n_in; (void)out_size; (void)ws_size;
  const float* inputs = (const float*)d_in[0];
  const float* times  = (const float*)d_in[1];
  const float* Wxh_w  = (const float*)d_in[2];
  const float* Wxh_b  = (const float*)d_in[3];
  const float* Whh_w  = (const float*)d_in[4];
  const float* tau    = (const float*)d_in[5];
  const float* s_p    = (const float*)d_in[6];
  unsigned char* ws = (unsigned char*)d_ws;
  float* out = (float*)d_out;

  hipMemsetAsync(ws + OFF_H0 + HB_SLOT, 0, HB_SLOT, stream);
  hipMemsetAsync(ws + OFF_H1 + HB_SLOT, 0, HB_SLOT, stream);
  hipMemsetAsync(ws + OFF_H0F + HF_SLOT, 0, HF_SLOT, stream);
  hipMemsetAsync(ws + OFF_H1F + HF_SLOT, 0, HF_SLOT, stream);
  hipMemsetAsync(ws + OFF_C0, 0, 131072, stream);
  hipMemsetAsync(ws + OFF_C1, 0, 131072, stream);

  plstm_prep<<<8192, 256, 0, stream>>>(Wxh_w, Whh_w, times, tau, s_p, ws);

  for (int q = 0; q <= 1025; ++q)
    plstm_step<<<64, 256, 0, stream>>>(inputs, Wxh_b, Wxh_w, Whh_w, out, ws, q);
}